// Round 8
// baseline (195.680 us; speedup 1.0000x reference)
//
#include <hip/hip_runtime.h>
#include <stdint.h>

// GaussianKernelSimilarity: z[8192,1024] f32, expert_keys[4096,1024] f32
// out0 = exp(-max(|z|^2+|e|^2-2 z.e, 0)/2)  [8192,4096]
// out1 = softmax(out0, axis=-1) @ expert_keys [8192,1024]
//
// Round 8: (a) 512-thread / 8-wave (2Mx4N) 128x128 dbuf GEMM -> 16 waves/CU
// (4/SIMD) for latency hiding of epilogue VALU + store drain; (b) epilogue
// computes exp ONCE per element: stage sim in LDS, transposed readback
// computes es=exp(sim) once for BOTH Wb and rowsum (round 7 did it twice:
// 192 exps/thread-equiv ~ K-loop MFMA cycles). sim stores non-temporal
// full-line.

#define M_TOK 8192
#define N_EXP 4096
#define D_DIM 1024

typedef __attribute__((ext_vector_type(4))) float f32x4;
typedef __attribute__((ext_vector_type(8))) short short8;
typedef __attribute__((ext_vector_type(4))) unsigned short u16x4;
typedef unsigned short u16;
typedef unsigned int u32;

__device__ __forceinline__ u16 f32_to_bf16(float f) {
  u32 u = __builtin_bit_cast(u32, f);
  u += 0x7fff + ((u >> 16) & 1);   // round-to-nearest-even
  return (u16)(u >> 16);
}

__device__ __forceinline__ void async16(const void* g, void* l) {
  __builtin_amdgcn_global_load_lds((__attribute__((address_space(1))) void*)(g),
                                   (__attribute__((address_space(3))) void*)(l),
                                   16, 0, 0);
}

// ---- prep: f32 -> bf16 convert + row |.|^2 for BOTH z and e (one launch) --
__global__ __launch_bounds__(256) void prep_convert2(const float* __restrict__ zsrc,
                                                     const float* __restrict__ esrc,
                                                     u16* __restrict__ zdst,
                                                     u16* __restrict__ edst,
                                                     float* __restrict__ zsq,
                                                     float* __restrict__ esq) {
  int row = blockIdx.x;
  const float* src;
  u16* dst;
  float* sq;
  if (row < M_TOK) {
    src = zsrc + (size_t)row * D_DIM;
    dst = zdst + (size_t)row * D_DIM;
    sq = zsq + row;
  } else {
    int r = row - M_TOK;
    src = esrc + (size_t)r * D_DIM;
    dst = edst + (size_t)r * D_DIM;
    sq = esq + r;
  }
  int t = threadIdx.x;                       // 256 threads, 4 elems each
  const float4 v = ((const float4*)src)[t];
  ushort4 h;
  h.x = f32_to_bf16(v.x); h.y = f32_to_bf16(v.y);
  h.z = f32_to_bf16(v.z); h.w = f32_to_bf16(v.w);
  ((ushort4*)dst)[t] = h;
  float p = v.x * v.x + v.y * v.y + v.z * v.z + v.w * v.w;
#pragma unroll
  for (int off = 1; off < 64; off <<= 1) p += __shfl_xor(p, off, 64);
  __shared__ float partial[4];
  if ((t & 63) == 0) partial[t >> 6] = p;
  __syncthreads();
  if (t == 0) *sq = partial[0] + partial[1] + partial[2] + partial[3];
}

// ---- bf16 transpose: eb[4096][1024] -> ebT[1024][4096] --------------------
__global__ __launch_bounds__(256) void transpose_bf16(const u16* __restrict__ src,
                                                      u16* __restrict__ dst) {
  __shared__ u16 tile[64][65];
  int e0 = blockIdx.x * 64;
  int d0 = blockIdx.y * 64;
  int t = threadIdx.x;
  int lr = t >> 4;
  int lc = (t & 15) * 4;
#pragma unroll
  for (int r8 = 0; r8 < 4; ++r8) {
    int row = lr + r8 * 16;
    ushort4 v = *(const ushort4*)(src + (size_t)(e0 + row) * D_DIM + d0 + lc);
    tile[row][lc + 0] = v.x; tile[row][lc + 1] = v.y;
    tile[row][lc + 2] = v.z; tile[row][lc + 3] = v.w;
  }
  __syncthreads();
#pragma unroll
  for (int r8 = 0; r8 < 4; ++r8) {
    int dl = lr + r8 * 16;
    ushort4 v;
    v.x = tile[lc + 0][dl]; v.y = tile[lc + 1][dl];
    v.z = tile[lc + 2][dl]; v.w = tile[lc + 3][dl];
    *(ushort4*)(dst + (size_t)(d0 + dl) * N_EXP + e0 + lc) = v;
  }
}

// ---- gemm_bt: C[M,N] = A[M,K] * Bt[N,K]^T, bf16 MFMA 16x16x32 -------------
// 128x128 tile, BK=64, 512 threads = 8 waves (2M x 4N); per-wave output
// 64 rows x 32 cols, acc[4][2]. Double-buffered LDS (64 KiB total).
// Per K-step: issue next tile's 4 global_load_lds per thread, ds_read+MFMA
// current, one barrier (compiler drains vmcnt/lgkm).
// SWAPPED operands mfma(bf, af, acc):
//   m-row = lane&15 (+mi*16+wr*64), n-col = (lane>>4)*4+reg (+ni*16+wc*32)
// EPI=1 epilogue, per (wave,mi) 16x32 tile:
//   phase 1: dist2 -> sim = exp(-d2/2); stage sim in wave-private LDS
//   phase 2 (transposed): read 4 row-consecutive sims; nt full-line store to
//   out; es = exp(sim) ONCE -> Wb store + 8-lane shfl rowsum + atomicAdd.
// EPI=0: store acc * (1/scale[row]).
template <int EPI>
__global__ __launch_bounds__(512, 4) void gemm_bt(const u16* __restrict__ A,
                                                  const u16* __restrict__ Bt,
                                                  int Mdim, int Ndim, int Kdim,
                                                  float* __restrict__ out, int ldo,
                                                  const float* __restrict__ a_sq,
                                                  const float* __restrict__ b_sq,
                                                  float* __restrict__ rowsum,
                                                  u16* __restrict__ wb,
                                                  const float* __restrict__ scale) {
  constexpr int BM = 128, BN = 128, BK = 64;
  __shared__ __align__(16) u16 smA[2 * BM * BK];   // 32 KiB
  __shared__ __align__(16) u16 smB[2 * BN * BK];   // 32 KiB

  const int nTilesN = Ndim / BN;
  const int nwg = (Mdim / BM) * nTilesN;
  const int cpx = nwg >> 3;
  const int wg = blockIdx.x;
  const int swz = (wg & 7) * cpx + (wg >> 3);      // XCD-aware swizzle
  const int m0 = (swz / nTilesN) * BM;
  const int n0 = (swz % nTilesN) * BN;

  const int t = threadIdx.x;
  const int l = t & 63;
  const int w = t >> 6;          // wave 0..7
  const int wr = w >> 2;         // 0..1 (M)
  const int wc = w & 3;          // 0..3 (N)
  const int lr8 = l >> 3;
  const int cswz = (((l & 7) ^ lr8) << 3);
  const int s0 = w * 2, s1 = w * 2 + 1;    // staging segments (16 per operand)
  const int str0 = s0 * 8 + lr8, str1 = s1 * 8 + lr8;

  f32x4 acc[4][2];
#pragma unroll
  for (int i = 0; i < 4; ++i)
#pragma unroll
    for (int j = 0; j < 2; ++j) acc[i][j] = (f32x4){0.f, 0.f, 0.f, 0.f};

  const int nIter = Kdim / BK;
  // prologue: stage tile 0 into buffer 0
  async16(A + (size_t)(m0 + str0) * Kdim + cswz, smA + s0 * 512);
  async16(A + (size_t)(m0 + str1) * Kdim + cswz, smA + s1 * 512);
  async16(Bt + (size_t)(n0 + str0) * Kdim + cswz, smB + s0 * 512);
  async16(Bt + (size_t)(n0 + str1) * Kdim + cswz, smB + s1 * 512);
  __syncthreads();

  int cur = 0;
  for (int it = 0; it < nIter; ++it) {
    if (it + 1 < nIter) {
      const int k0 = (it + 1) * BK;
      const int nb = (cur ^ 1) * 8192;
      async16(A + (size_t)(m0 + str0) * Kdim + k0 + cswz, smA + nb + s0 * 512);
      async16(A + (size_t)(m0 + str1) * Kdim + k0 + cswz, smA + nb + s1 * 512);
      async16(Bt + (size_t)(n0 + str0) * Kdim + k0 + cswz, smB + nb + s0 * 512);
      async16(Bt + (size_t)(n0 + str1) * Kdim + k0 + cswz, smB + nb + s1 * 512);
    }
    const int cbase = cur * 8192;
#pragma unroll
    for (int ks = 0; ks < 2; ++ks) {
      short8 af[4], bf[2];
      const int lrow = l & 15;
      const int kb = ks * 64 + ((l >> 4) << 4);
#pragma unroll
      for (int mi = 0; mi < 4; ++mi) {
        int row = wr * 64 + mi * 16 + lrow;
        int addr = row * 128 + (kb ^ ((row & 7) << 4));
        af[mi] = *(const short8*)(smA + cbase + (addr >> 1));
      }
#pragma unroll
      for (int ni = 0; ni < 2; ++ni) {
        int row = wc * 32 + ni * 16 + lrow;
        int addr = row * 128 + (kb ^ ((row & 7) << 4));
        bf[ni] = *(const short8*)(smB + cbase + (addr >> 1));
      }
#pragma unroll
      for (int mi = 0; mi < 4; ++mi)
#pragma unroll
        for (int ni = 0; ni < 2; ++ni)
          acc[mi][ni] = __builtin_amdgcn_mfma_f32_16x16x32_bf16(
              bf[ni], af[mi], acc[mi][ni], 0, 0, 0);
    }
    __syncthreads();   // drains vmcnt/lgkm; next buffer ready, cur reusable
    cur ^= 1;
  }
  // all waves past their last ds_read -> smA reusable as epilogue scratch

  const int lcol = l & 15;
  const int rgrp = l >> 4;
  if (EPI == 1) {
    // wave-private transpose scratch: 16 rows x 36 floats = 2304 B x 8 waves
    float* ldsT = ((float*)smA) + w * (16 * 36);
    const int rr = l >> 3;        // 0..7
    const int c4 = (l & 7) * 4;   // col within 32
#pragma unroll
    for (int mi = 0; mi < 4; ++mi) {
      int grow = m0 + wr * 64 + mi * 16 + lcol;
      float zq = a_sq[grow];
      // phase 1: sim = exp(-d2/2), stage in LDS (no es here)
#pragma unroll
      for (int ni = 0; ni < 2; ++ni) {
        int ncol = n0 + wc * 32 + ni * 16 + rgrp * 4;
        f32x4 eqv = *(const f32x4*)(b_sq + ncol);
        f32x4 simv;
#pragma unroll
        for (int r = 0; r < 4; ++r) {
          float dist2 = fmaxf(zq + eqv[r] - 2.0f * acc[mi][ni][r], 0.0f);
          simv[r] = __expf(-0.5f * dist2);
        }
        *(f32x4*)(ldsT + lcol * 36 + ni * 16 + rgrp * 4) = simv;
      }
      asm volatile("s_waitcnt lgkmcnt(0)" ::: "memory");
      // phase 2: transposed readback; es computed ONCE per element
#pragma unroll
      for (int pass = 0; pass < 2; ++pass) {
        int rrow = pass * 8 + rr;                 // 0..15
        f32x4 sv = *(const f32x4*)(ldsT + rrow * 36 + c4);
        int growr = m0 + wr * 64 + mi * 16 + rrow;
        size_t gbase = (size_t)growr * ldo + (n0 + wc * 32 + c4);
        __builtin_nontemporal_store(sv, (f32x4*)(out + gbase));
        f32x4 es;
#pragma unroll
        for (int r = 0; r < 4; ++r) es[r] = __expf(sv[r]);
        if (wb) {
          u16x4 wv;
          wv.x = f32_to_bf16(es[0]); wv.y = f32_to_bf16(es[1]);
          wv.z = f32_to_bf16(es[2]); wv.w = f32_to_bf16(es[3]);
          *(u16x4*)(wb + gbase) = wv;
        }
        float p = es[0] + es[1] + es[2] + es[3];
        p += __shfl_xor(p, 1, 64);
        p += __shfl_xor(p, 2, 64);
        p += __shfl_xor(p, 4, 64);
        if ((l & 7) == 0) atomicAdd(&rowsum[growr], p);
      }
    }
  } else {
#pragma unroll
    for (int mi = 0; mi < 4; ++mi) {
      int grow = m0 + wr * 64 + mi * 16 + lcol;
      float s = scale ? (1.0f / scale[grow]) : 1.0f;
#pragma unroll
      for (int ni = 0; ni < 2; ++ni) {
        int ncol = n0 + wc * 32 + ni * 16 + rgrp * 4;
        f32x4 v = acc[mi][ni] * s;
        *(f32x4*)(out + (size_t)grow * ldo + ncol) = v;
      }
    }
  }
}

// ---- weights (fallback path only) -----------------------------------------
__global__ __launch_bounds__(256) void weights_kernel(const float* __restrict__ sim,
                                                      const float* __restrict__ rowsum,
                                                      u16* __restrict__ wb) {
  size_t i = ((size_t)blockIdx.x * 256 + threadIdx.x) * 8;
  int row = (int)(i >> 12);
  float inv = 1.0f / rowsum[row];
  float4 a = *(const float4*)(sim + i);
  float4 b = *(const float4*)(sim + i + 4);
  u32 w0 = (u32)f32_to_bf16(__expf(a.x) * inv) | ((u32)f32_to_bf16(__expf(a.y) * inv) << 16);
  u32 w1 = (u32)f32_to_bf16(__expf(a.z) * inv) | ((u32)f32_to_bf16(__expf(a.w) * inv) << 16);
  u32 w2 = (u32)f32_to_bf16(__expf(b.x) * inv) | ((u32)f32_to_bf16(__expf(b.y) * inv) << 16);
  u32 w3 = (u32)f32_to_bf16(__expf(b.z) * inv) | ((u32)f32_to_bf16(__expf(b.w) * inv) << 16);
  uint4 o; o.x = w0; o.y = w1; o.z = w2; o.w = w3;
  *(uint4*)(wb + i) = o;
}

extern "C" void kernel_launch(void* const* d_in, const int* in_sizes, int n_in,
                              void* d_out, int out_size, void* d_ws, size_t ws_size,
                              hipStream_t stream) {
  const float* z = (const float*)d_in[0];
  const float* e = (const float*)d_in[1];
  float* out = (float*)d_out;
  float* sim = out;                                   // [8192,4096]
  float* wout = out + (size_t)M_TOK * N_EXP;          // [8192,1024]

  char* ws = (char*)d_ws;
  const size_t MB = (size_t)1 << 20;
  const bool fused = ws_size >= 96 * MB + 80 * 1024;

  if (fused) {
    u16* zb  = (u16*)ws;                              // 16 MiB
    u16* eb  = (u16*)(ws + 16 * MB);                  // 8 MiB
    u16* ebT = (u16*)(ws + 24 * MB);                  // 8 MiB
    u16* Wb  = (u16*)(ws + 32 * MB);                  // 64 MiB
    float* z_sq   = (float*)(ws + 96 * MB);
    float* e_sq   = (float*)(ws + 96 * MB + 32768);
    float* rowsum = (float*)(ws + 96 * MB + 49152);

    prep_convert2<<<M_TOK + N_EXP, 256, 0, stream>>>(z, e, zb, eb, z_sq, e_sq);
    transpose_bf16<<<dim3(N_EXP / 64, D_DIM / 64), 256, 0, stream>>>(eb, ebT);
    (void)hipMemsetAsync(rowsum, 0, M_TOK * sizeof(float), stream);

    // GEMM1: sim -> out (nt full-line), bf16(exp(sim)) -> Wb, rowsum
    gemm_bt<1><<<(M_TOK / 128) * (N_EXP / 128), 512, 0, stream>>>(
        zb, eb, M_TOK, N_EXP, D_DIM, sim, N_EXP, z_sq, e_sq, rowsum, Wb, nullptr);

    // GEMM2: wout = (expsim @ E) / rowsum[row]
    gemm_bt<0><<<(M_TOK / 128) * (D_DIM / 128), 512, 0, stream>>>(
        Wb, ebT, M_TOK, D_DIM, N_EXP, wout, D_DIM, nullptr, nullptr, nullptr,
        nullptr, rowsum);
  } else {
    u16* Wb  = (u16*)ws;
    u16* zb  = (u16*)ws;
    u16* eb  = (u16*)(ws + 64 * MB);
    u16* ebT = (u16*)(ws + 72 * MB);
    float* z_sq   = (float*)(ws + 80 * MB);
    float* e_sq   = (float*)(ws + 80 * MB + 32768);
    float* rowsum = (float*)(ws + 80 * MB + 49152);

    prep_convert2<<<M_TOK + N_EXP, 256, 0, stream>>>(z, e, zb, eb, z_sq, e_sq);
    transpose_bf16<<<dim3(N_EXP / 64, D_DIM / 64), 256, 0, stream>>>(eb, ebT);
    (void)hipMemsetAsync(rowsum, 0, M_TOK * sizeof(float), stream);

    gemm_bt<1><<<(M_TOK / 128) * (N_EXP / 128), 512, 0, stream>>>(
        zb, eb, M_TOK, N_EXP, D_DIM, sim, N_EXP, z_sq, e_sq, rowsum, nullptr, nullptr);

    weights_kernel<<<(M_TOK * (size_t)N_EXP) / (8 * 256), 256, 0, stream>>>(sim, rowsum, Wb);

    gemm_bt<0><<<(M_TOK / 128) * (D_DIM / 128), 512, 0, stream>>>(
        Wb, ebT, M_TOK, D_DIM, N_EXP, wout, D_DIM, nullptr, nullptr, nullptr,
        nullptr, nullptr);
  }
}

// Round 9
// 187.862 us; speedup vs baseline: 1.0416x; 1.0416x over previous
//
#include <hip/hip_runtime.h>
#include <stdint.h>

// GaussianKernelSimilarity: z[8192,1024] f32, expert_keys[4096,1024] f32
// out0 = exp(-max(|z|^2+|e|^2-2 z.e, 0)/2)  [8192,4096]
// out1 = softmax(out0, axis=-1) @ expert_keys [8192,1024]
//
// Round 9: break the two invariants shared by all previous rounds:
//  (1) NO atomics: GEMM1 writes partial rowsums rs_part[nt*4+wc][row]
//      (plain stores, deterministic); rowsum_reduce kernel folds 128
//      partials/row before GEMM2. Removes ~1M device-scope atomicAdds
//      that funneled into few L2 lines.
//  (2) L2-aware super-tile mapping for GEMM1: each XCD owns an 8-m-tile
//      stripe; within it 8m x 4n super-tiles -> concurrent WS ~4MB (fits
//      XCD L2); all XCDs share the same B-panels at the same time (L3).
// K-loop/epilogue otherwise = round 8 (512 thr, 8 waves, dbuf, LDS
// transpose, exp-once, nt sim stores).

#define M_TOK 8192
#define N_EXP 4096
#define D_DIM 1024

typedef __attribute__((ext_vector_type(4))) float f32x4;
typedef __attribute__((ext_vector_type(8))) short short8;
typedef __attribute__((ext_vector_type(4))) unsigned short u16x4;
typedef unsigned short u16;
typedef unsigned int u32;

__device__ __forceinline__ u16 f32_to_bf16(float f) {
  u32 u = __builtin_bit_cast(u32, f);
  u += 0x7fff + ((u >> 16) & 1);   // round-to-nearest-even
  return (u16)(u >> 16);
}

__device__ __forceinline__ void async16(const void* g, void* l) {
  __builtin_amdgcn_global_load_lds((__attribute__((address_space(1))) void*)(g),
                                   (__attribute__((address_space(3))) void*)(l),
                                   16, 0, 0);
}

// ---- prep: f32 -> bf16 convert + row |.|^2 for BOTH z and e (one launch) --
__global__ __launch_bounds__(256) void prep_convert2(const float* __restrict__ zsrc,
                                                     const float* __restrict__ esrc,
                                                     u16* __restrict__ zdst,
                                                     u16* __restrict__ edst,
                                                     float* __restrict__ zsq,
                                                     float* __restrict__ esq) {
  int row = blockIdx.x;
  const float* src;
  u16* dst;
  float* sq;
  if (row < M_TOK) {
    src = zsrc + (size_t)row * D_DIM;
    dst = zdst + (size_t)row * D_DIM;
    sq = zsq + row;
  } else {
    int r = row - M_TOK;
    src = esrc + (size_t)r * D_DIM;
    dst = edst + (size_t)r * D_DIM;
    sq = esq + r;
  }
  int t = threadIdx.x;                       // 256 threads, 4 elems each
  const float4 v = ((const float4*)src)[t];
  ushort4 h;
  h.x = f32_to_bf16(v.x); h.y = f32_to_bf16(v.y);
  h.z = f32_to_bf16(v.z); h.w = f32_to_bf16(v.w);
  ((ushort4*)dst)[t] = h;
  float p = v.x * v.x + v.y * v.y + v.z * v.z + v.w * v.w;
#pragma unroll
  for (int off = 1; off < 64; off <<= 1) p += __shfl_xor(p, off, 64);
  __shared__ float partial[4];
  if ((t & 63) == 0) partial[t >> 6] = p;
  __syncthreads();
  if (t == 0) *sq = partial[0] + partial[1] + partial[2] + partial[3];
}

// ---- bf16 transpose: eb[4096][1024] -> ebT[1024][4096] --------------------
__global__ __launch_bounds__(256) void transpose_bf16(const u16* __restrict__ src,
                                                      u16* __restrict__ dst) {
  __shared__ u16 tile[64][65];
  int e0 = blockIdx.x * 64;
  int d0 = blockIdx.y * 64;
  int t = threadIdx.x;
  int lr = t >> 4;
  int lc = (t & 15) * 4;
#pragma unroll
  for (int r8 = 0; r8 < 4; ++r8) {
    int row = lr + r8 * 16;
    ushort4 v = *(const ushort4*)(src + (size_t)(e0 + row) * D_DIM + d0 + lc);
    tile[row][lc + 0] = v.x; tile[row][lc + 1] = v.y;
    tile[row][lc + 2] = v.z; tile[row][lc + 3] = v.w;
  }
  __syncthreads();
#pragma unroll
  for (int r8 = 0; r8 < 4; ++r8) {
    int dl = lr + r8 * 16;
    ushort4 v;
    v.x = tile[lc + 0][dl]; v.y = tile[lc + 1][dl];
    v.z = tile[lc + 2][dl]; v.w = tile[lc + 3][dl];
    *(ushort4*)(dst + (size_t)(d0 + dl) * N_EXP + e0 + lc) = v;
  }
}

// ---- rowsum reduce: rowsum[r] = sum_j rs_part[j][r], j in [0,128) ---------
__global__ __launch_bounds__(256) void rowsum_reduce(const float* __restrict__ part,
                                                     float* __restrict__ rowsum) {
  int r = blockIdx.x * 256 + threadIdx.x;    // 32 blocks x 256 = 8192 rows
  float s = 0.f;
#pragma unroll 8
  for (int j = 0; j < 128; ++j) s += part[(size_t)j * M_TOK + r];
  rowsum[r] = s;
}

// ---- gemm_bt: C[M,N] = A[M,K] * Bt[N,K]^T, bf16 MFMA 16x16x32 -------------
// 128x128 tile, BK=64, 512 threads = 8 waves (2M x 4N); per-wave output
// 64 rows x 32 cols, acc[4][2]. Double-buffered LDS (64 KiB total).
// SWAPPED operands mfma(bf, af, acc):
//   m-row = lane&15 (+mi*16+wr*64), n-col = (lane>>4)*4+reg (+ni*16+wc*32)
// Block mapping:
//   EPI=1 (GEMM1, 64x32 tiles): XCD stripe + 8m x 4n super-tiles for L2.
//   EPI=0: plain XCD chunk swizzle.
// EPI=1 epilogue: LDS-transposed full-line stores; sim nt; es=exp(sim) once
//   -> Wb + 8-lane shfl partial rowsum -> rs_part[nt*4+wc][row] (NO atomics).
// EPI=0: store acc * (1/scale[row]).
template <int EPI>
__global__ __launch_bounds__(512, 4) void gemm_bt(const u16* __restrict__ A,
                                                  const u16* __restrict__ Bt,
                                                  int Mdim, int Ndim, int Kdim,
                                                  float* __restrict__ out, int ldo,
                                                  const float* __restrict__ a_sq,
                                                  const float* __restrict__ b_sq,
                                                  float* __restrict__ rs_part,
                                                  u16* __restrict__ wb,
                                                  const float* __restrict__ scale) {
  constexpr int BM = 128, BN = 128, BK = 64;
  __shared__ __align__(16) u16 smA[2 * BM * BK];   // 32 KiB
  __shared__ __align__(16) u16 smB[2 * BN * BK];   // 32 KiB

  const int wg = blockIdx.x;
  int m0, n0, ntile = 0;
  if (EPI == 1) {
    // GEMM1: 64 m-tiles x 32 n-tiles. XCD stripe (8 m-tiles) + 8m x 4n supers
    const int xcd = wg & 7;
    const int idx = wg >> 3;          // 0..255 within XCD
    const int sup = idx >> 5;         // 0..7  -> n-group
    const int mloc = (idx & 31) >> 2; // 0..7
    const int nloc = idx & 3;         // 0..3
    m0 = (xcd * 8 + mloc) * BM;
    ntile = sup * 4 + nloc;
    n0 = ntile * BN;
  } else {
    const int nTilesN = Ndim / BN;
    const int nwg = (Mdim / BM) * nTilesN;
    const int cpx = nwg >> 3;
    const int swz = (wg & 7) * cpx + (wg >> 3);
    m0 = (swz / nTilesN) * BM;
    n0 = (swz % nTilesN) * BN;
  }

  const int t = threadIdx.x;
  const int l = t & 63;
  const int w = t >> 6;          // wave 0..7
  const int wr = w >> 2;         // 0..1 (M)
  const int wc = w & 3;          // 0..3 (N)
  const int lr8 = l >> 3;
  const int cswz = (((l & 7) ^ lr8) << 3);
  const int s0 = w * 2, s1 = w * 2 + 1;    // staging segments (16 per operand)
  const int str0 = s0 * 8 + lr8, str1 = s1 * 8 + lr8;

  f32x4 acc[4][2];
#pragma unroll
  for (int i = 0; i < 4; ++i)
#pragma unroll
    for (int j = 0; j < 2; ++j) acc[i][j] = (f32x4){0.f, 0.f, 0.f, 0.f};

  const int nIter = Kdim / BK;
  // prologue: stage tile 0 into buffer 0
  async16(A + (size_t)(m0 + str0) * Kdim + cswz, smA + s0 * 512);
  async16(A + (size_t)(m0 + str1) * Kdim + cswz, smA + s1 * 512);
  async16(Bt + (size_t)(n0 + str0) * Kdim + cswz, smB + s0 * 512);
  async16(Bt + (size_t)(n0 + str1) * Kdim + cswz, smB + s1 * 512);
  __syncthreads();

  int cur = 0;
  for (int it = 0; it < nIter; ++it) {
    if (it + 1 < nIter) {
      const int k0 = (it + 1) * BK;
      const int nb = (cur ^ 1) * 8192;
      async16(A + (size_t)(m0 + str0) * Kdim + k0 + cswz, smA + nb + s0 * 512);
      async16(A + (size_t)(m0 + str1) * Kdim + k0 + cswz, smA + nb + s1 * 512);
      async16(Bt + (size_t)(n0 + str0) * Kdim + k0 + cswz, smB + nb + s0 * 512);
      async16(Bt + (size_t)(n0 + str1) * Kdim + k0 + cswz, smB + nb + s1 * 512);
    }
    const int cbase = cur * 8192;
#pragma unroll
    for (int ks = 0; ks < 2; ++ks) {
      short8 af[4], bf[2];
      const int lrow = l & 15;
      const int kb = ks * 64 + ((l >> 4) << 4);
#pragma unroll
      for (int mi = 0; mi < 4; ++mi) {
        int row = wr * 64 + mi * 16 + lrow;
        int addr = row * 128 + (kb ^ ((row & 7) << 4));
        af[mi] = *(const short8*)(smA + cbase + (addr >> 1));
      }
#pragma unroll
      for (int ni = 0; ni < 2; ++ni) {
        int row = wc * 32 + ni * 16 + lrow;
        int addr = row * 128 + (kb ^ ((row & 7) << 4));
        bf[ni] = *(const short8*)(smB + cbase + (addr >> 1));
      }
#pragma unroll
      for (int mi = 0; mi < 4; ++mi)
#pragma unroll
        for (int ni = 0; ni < 2; ++ni)
          acc[mi][ni] = __builtin_amdgcn_mfma_f32_16x16x32_bf16(
              bf[ni], af[mi], acc[mi][ni], 0, 0, 0);
    }
    __syncthreads();   // drains vmcnt/lgkm; next buffer ready, cur reusable
    cur ^= 1;
  }
  // all waves past their last ds_read -> smA reusable as epilogue scratch

  const int lcol = l & 15;
  const int rgrp = l >> 4;
  if (EPI == 1) {
    // wave-private transpose scratch: 16 rows x 36 floats = 2304 B x 8 waves
    float* ldsT = ((float*)smA) + w * (16 * 36);
    const int rr = l >> 3;        // 0..7
    const int c4 = (l & 7) * 4;   // col within 32
    const int slot = ntile * 4 + wc;   // partial-rowsum slot, 0..127
#pragma unroll
    for (int mi = 0; mi < 4; ++mi) {
      int grow = m0 + wr * 64 + mi * 16 + lcol;
      float zq = a_sq[grow];
      // phase 1: sim = exp(-d2/2), stage in LDS
#pragma unroll
      for (int ni = 0; ni < 2; ++ni) {
        int ncol = n0 + wc * 32 + ni * 16 + rgrp * 4;
        f32x4 eqv = *(const f32x4*)(b_sq + ncol);
        f32x4 simv;
#pragma unroll
        for (int r = 0; r < 4; ++r) {
          float dist2 = fmaxf(zq + eqv[r] - 2.0f * acc[mi][ni][r], 0.0f);
          simv[r] = __expf(-0.5f * dist2);
        }
        *(f32x4*)(ldsT + lcol * 36 + ni * 16 + rgrp * 4) = simv;
      }
      asm volatile("s_waitcnt lgkmcnt(0)" ::: "memory");
      // phase 2: transposed readback; es computed ONCE per element
#pragma unroll
      for (int pass = 0; pass < 2; ++pass) {
        int rrow = pass * 8 + rr;                 // 0..15
        f32x4 sv = *(const f32x4*)(ldsT + rrow * 36 + c4);
        int growr = m0 + wr * 64 + mi * 16 + rrow;
        size_t gbase = (size_t)growr * ldo + (n0 + wc * 32 + c4);
        __builtin_nontemporal_store(sv, (f32x4*)(out + gbase));
        f32x4 es;
#pragma unroll
        for (int r = 0; r < 4; ++r) es[r] = __expf(sv[r]);
        if (wb) {
          u16x4 wv;
          wv.x = f32_to_bf16(es[0]); wv.y = f32_to_bf16(es[1]);
          wv.z = f32_to_bf16(es[2]); wv.w = f32_to_bf16(es[3]);
          *(u16x4*)(wb + gbase) = wv;
        }
        float p = es[0] + es[1] + es[2] + es[3];
        p += __shfl_xor(p, 1, 64);
        p += __shfl_xor(p, 2, 64);
        p += __shfl_xor(p, 4, 64);
        // deterministic partial store (replaces atomicAdd): 8 consecutive
        // rows per wave-instr, one slot per (ntile, wc)
        if ((l & 7) == 0) rs_part[(size_t)slot * M_TOK + growr] = p;
      }
    }
  } else {
#pragma unroll
    for (int mi = 0; mi < 4; ++mi) {
      int grow = m0 + wr * 64 + mi * 16 + lcol;
      float s = scale ? (1.0f / scale[grow]) : 1.0f;
#pragma unroll
      for (int ni = 0; ni < 2; ++ni) {
        int ncol = n0 + wc * 32 + ni * 16 + rgrp * 4;
        f32x4 v = acc[mi][ni] * s;
        *(f32x4*)(out + (size_t)grow * ldo + ncol) = v;
      }
    }
  }
}

// ---- weights (fallback path only) -----------------------------------------
__global__ __launch_bounds__(256) void weights_kernel(const float* __restrict__ sim,
                                                      const float* __restrict__ rowsum,
                                                      u16* __restrict__ wb) {
  size_t i = ((size_t)blockIdx.x * 256 + threadIdx.x) * 8;
  int row = (int)(i >> 12);
  float inv = 1.0f / rowsum[row];
  float4 a = *(const float4*)(sim + i);
  float4 b = *(const float4*)(sim + i + 4);
  u32 w0 = (u32)f32_to_bf16(__expf(a.x) * inv) | ((u32)f32_to_bf16(__expf(a.y) * inv) << 16);
  u32 w1 = (u32)f32_to_bf16(__expf(a.z) * inv) | ((u32)f32_to_bf16(__expf(a.w) * inv) << 16);
  u32 w2 = (u32)f32_to_bf16(__expf(b.x) * inv) | ((u32)f32_to_bf16(__expf(b.y) * inv) << 16);
  u32 w3 = (u32)f32_to_bf16(__expf(b.z) * inv) | ((u32)f32_to_bf16(__expf(b.w) * inv) << 16);
  uint4 o; o.x = w0; o.y = w1; o.z = w2; o.w = w3;
  *(uint4*)(wb + i) = o;
}

extern "C" void kernel_launch(void* const* d_in, const int* in_sizes, int n_in,
                              void* d_out, int out_size, void* d_ws, size_t ws_size,
                              hipStream_t stream) {
  const float* z = (const float*)d_in[0];
  const float* e = (const float*)d_in[1];
  float* out = (float*)d_out;
  float* sim = out;                                   // [8192,4096]
  float* wout = out + (size_t)M_TOK * N_EXP;          // [8192,1024]

  char* ws = (char*)d_ws;
  const size_t MB = (size_t)1 << 20;
  const bool fused = ws_size >= 100 * MB + 96 * 1024;

  if (fused) {
    u16* zb  = (u16*)ws;                              // 16 MiB
    u16* eb  = (u16*)(ws + 16 * MB);                  // 8 MiB
    u16* ebT = (u16*)(ws + 24 * MB);                  // 8 MiB
    u16* Wb  = (u16*)(ws + 32 * MB);                  // 64 MiB
    float* rs_part = (float*)(ws + 96 * MB);          // 4 MiB (128 x 8192)
    float* z_sq   = (float*)(ws + 100 * MB);
    float* e_sq   = (float*)(ws + 100 * MB + 32768);
    float* rowsum = (float*)(ws + 100 * MB + 49152);

    prep_convert2<<<M_TOK + N_EXP, 256, 0, stream>>>(z, e, zb, eb, z_sq, e_sq);
    transpose_bf16<<<dim3(N_EXP / 64, D_DIM / 64), 256, 0, stream>>>(eb, ebT);

    // GEMM1: sim -> out (nt), bf16(exp(sim)) -> Wb, partial rowsums
    gemm_bt<1><<<(M_TOK / 128) * (N_EXP / 128), 512, 0, stream>>>(
        zb, eb, M_TOK, N_EXP, D_DIM, sim, N_EXP, z_sq, e_sq, rs_part, Wb, nullptr);

    rowsum_reduce<<<M_TOK / 256, 256, 0, stream>>>(rs_part, rowsum);

    // GEMM2: wout = (expsim @ E) / rowsum[row]
    gemm_bt<0><<<(M_TOK / 128) * (D_DIM / 128), 512, 0, stream>>>(
        Wb, ebT, M_TOK, D_DIM, N_EXP, wout, D_DIM, nullptr, nullptr, nullptr,
        nullptr, rowsum);
  } else {
    // fallback: zb aliases Wb, separate weights pass
    u16* Wb  = (u16*)ws;                              // 64 MiB
    u16* zb  = (u16*)ws;                              // aliases Wb
    u16* eb  = (u16*)(ws + 64 * MB);                  // 8 MiB
    u16* ebT = (u16*)(ws + 72 * MB);                  // 8 MiB
    float* rs_part = (float*)(ws + 80 * MB);          // 4 MiB
    float* z_sq   = (float*)(ws + 84 * MB);
    float* e_sq   = (float*)(ws + 84 * MB + 32768);
    float* rowsum = (float*)(ws + 84 * MB + 49152);

    prep_convert2<<<M_TOK + N_EXP, 256, 0, stream>>>(z, e, zb, eb, z_sq, e_sq);
    transpose_bf16<<<dim3(N_EXP / 64, D_DIM / 64), 256, 0, stream>>>(eb, ebT);

    gemm_bt<1><<<(M_TOK / 128) * (N_EXP / 128), 512, 0, stream>>>(
        zb, eb, M_TOK, N_EXP, D_DIM, sim, N_EXP, z_sq, e_sq, rs_part, nullptr, nullptr);

    rowsum_reduce<<<M_TOK / 256, 256, 0, stream>>>(rs_part, rowsum);

    weights_kernel<<<(M_TOK * (size_t)N_EXP) / (8 * 256), 256, 0, stream>>>(sim, rowsum, Wb);

    gemm_bt<0><<<(M_TOK / 128) * (D_DIM / 128), 512, 0, stream>>>(
        Wb, ebT, M_TOK, D_DIM, N_EXP, wout, D_DIM, nullptr, nullptr, nullptr,
        nullptr, nullptr);
  }
}